// Round 4
// baseline (279.774 us; speedup 1.0000x reference)
//
#include <hip/hip_runtime.h>

#define TREES 64
#define NN 63        // internal nodes per tree
#define LL 64        // leaves per tree
#define CC 100       // classes
#define CPAD 112     // classes padded to 7*16
#define DD 512       // feature dim
#define BB 8192      // batch
#define BM 128       // rows per block
#define BK 64        // K tile (8 iterations)

typedef __attribute__((ext_vector_type(8))) _Float16 f16x8;
typedef __attribute__((ext_vector_type(4))) _Float16 f16x4;
typedef __attribute__((ext_vector_type(4))) float floatx4;

// ---- workspace layout (bytes) ----
#define XH_WS  0                  // [8192][512] f16  = 8388608
#define SWH_WS 8388608            // [64][64][512] f16 = 4194304 (node 63 zeroed)
#define W2T_WS 12582912           // [64][112][64] f16 = 917504
// total 13.5 MB

// ---- LDS layout (bytes), K-loop staging aliased by epilogue dec/lp ----
#define XS_OFF  0                 // [128][64] f16 = 16384 (chunk-swizzled)
#define WL_OFF  16384             // [128][64] f16 = 16384
#define DEC_OFF 0                 // [64 nodes][132 rows] f16 = 16896
#define LP_OFF  16896             // [128][64] f16 = 16384 (swizzled)
#define W2B_OFF 33280             // [112][64] f16 = 14336 (swizzled)
#define SMEM_BYTES 47616          // *3 = 142848 <= 160 KiB -> 3 blocks/CU

__device__ __forceinline__ void gl_lds16(const _Float16* g, char* lds) {
    __builtin_amdgcn_global_load_lds(
        (const __attribute__((address_space(1))) unsigned int*)g,
        (__attribute__((address_space(3))) unsigned int*)lds, 16, 0, 0);
}

// ---------------------------------------------------------------------------
// Prep A: convert x -> xh (f16) and sw -> swh (f16, node-padded to 64)
// one f16x8 chunk per thread; grid covers both arrays
// ---------------------------------------------------------------------------
__global__ __launch_bounds__(256) void cvt_kernel(
    const float* __restrict__ x, const float* __restrict__ sw,
    _Float16* __restrict__ xh, _Float16* __restrict__ swh)
{
    int i = blockIdx.x * 256 + threadIdx.x;
    if (i < 524288) {                       // x chunks: 8192*512/8
        const float4* s = (const float4*)(x + (size_t)i * 8);
        float4 a = s[0], b = s[1];
        f16x8 h;
        h[0]=(_Float16)a.x; h[1]=(_Float16)a.y; h[2]=(_Float16)a.z; h[3]=(_Float16)a.w;
        h[4]=(_Float16)b.x; h[5]=(_Float16)b.y; h[6]=(_Float16)b.z; h[7]=(_Float16)b.w;
        *(f16x8*)(xh + (size_t)i * 8) = h;
    } else {
        int j = i - 524288;                 // swh chunks: 64*64*512/8
        if (j < 262144) {
            int e = j * 8;
            int t = e >> 15, rem = e & 32767;
            int node = rem >> 9, k = rem & 511;
            f16x8 h = (f16x8)(_Float16)0.f;
            if (node < NN) {
                const float4* s = (const float4*)(sw + ((size_t)(t * NN + node) * DD + k));
                float4 a = s[0], b = s[1];
                h[0]=(_Float16)a.x; h[1]=(_Float16)a.y; h[2]=(_Float16)a.z; h[3]=(_Float16)a.w;
                h[4]=(_Float16)b.x; h[5]=(_Float16)b.y; h[6]=(_Float16)b.z; h[7]=(_Float16)b.w;
            }
            *(f16x8*)(swh + (size_t)e) = h;
        }
    }
}

// ---------------------------------------------------------------------------
// Prep B: w2T[t][c][l] = f16( tree_w[t] * softmax(leaf_logits[t,l,:])[c] )
// ---------------------------------------------------------------------------
__global__ __launch_bounds__(256) void prep_w2_kernel(
    const float* __restrict__ leaf_logits,
    const float* __restrict__ tree_w,
    _Float16* __restrict__ w2T)
{
    int row  = blockIdx.x * 4 + (threadIdx.x >> 6);   // 0..4095 (= t*64 + l)
    int lane = threadIdx.x & 63;
    int t = row >> 6, l = row & 63;
    const float* src = leaf_logits + (size_t)row * CC;
    float v0 = (lane < CC)      ? src[lane]      : -1e30f;
    float v1 = (lane + 64 < CC) ? src[lane + 64] : -1e30f;
    float m = fmaxf(v0, v1);
#pragma unroll
    for (int off = 32; off > 0; off >>= 1)
        m = fmaxf(m, __shfl_down(m, off, 64));
    m = __shfl(m, 0, 64);
    float e0 = (lane < CC)      ? __expf(v0 - m) : 0.f;
    float e1 = (lane + 64 < CC) ? __expf(v1 - m) : 0.f;
    float s = e0 + e1;
#pragma unroll
    for (int off = 32; off > 0; off >>= 1)
        s += __shfl_down(s, off, 64);
    s = __shfl(s, 0, 64);
    float scale = tree_w[t] / s;
    _Float16* base = w2T + (size_t)t * CPAD * LL;
    if (lane < CC)      base[(size_t)lane * LL + l]        = (_Float16)(e0 * scale);
    if (lane + 64 < CC) base[(size_t)(lane + 64) * LL + l] = (_Float16)(e1 * scale);
    if (lane < CPAD - CC) base[(size_t)(CC + lane) * LL + l] = (_Float16)0.f;
}

// ---------------------------------------------------------------------------
// Main: per block, 128 rows x 2 tree-pairs (4 trees), accumulate in regs.
// grid = (64, 16); block = 256 (4 waves 2x2, wave tile 64x64)
// K-loop staging via global_load_lds (16B), swizzle folded into global gather.
// ---------------------------------------------------------------------------
__global__ __launch_bounds__(256, 3) void forest_kernel(
    const _Float16* __restrict__ xh,   // [8192][512]
    const _Float16* __restrict__ swh,  // [64][64][512]
    const float* __restrict__ sb,      // [64][63]
    const _Float16* __restrict__ w2T,  // [64][112][64]
    float* __restrict__ out)           // [8192][100]
{
    __shared__ __align__(16) char smem[SMEM_BYTES];
    _Float16* xsh  = (_Float16*)(smem + XS_OFF);
    _Float16* wlh  = (_Float16*)(smem + WL_OFF);
    _Float16* dec  = (_Float16*)(smem + DEC_OFF);
    _Float16* lph  = (_Float16*)(smem + LP_OFF);
    _Float16* w2bh = (_Float16*)(smem + W2B_OFF);

    const int tid  = threadIdx.x;
    const int lane = tid & 63;
    const int wid  = tid >> 6;
    const int wy   = wid >> 1;
    const int wx   = wid & 1;
    const int quad = lane >> 4;
    const int l15  = lane & 15;
    const int Lr   = lane >> 3;          // 0..7 (row within 8-row load)
    const int csw  = (lane & 7) ^ Lr;    // swizzled source chunk
    const int b0   = blockIdx.x * BM;

    floatx4 oacc[2][7];
#pragma unroll
    for (int mi = 0; mi < 2; ++mi)
#pragma unroll
        for (int ni = 0; ni < 7; ++ni) oacc[mi][ni] = (floatx4)0.f;

    const int lrow = tid >> 1;       // 0..127 (leafprob row)
    const int half = tid & 1;

    // per-lane staging source base for x (row = b0 + 32*wid + Lr)
    const _Float16* xg = xh + (size_t)(b0 + 32 * wid + Lr) * DD + csw * 8;

    for (int pp = 0; pp < 2; ++pp) {
        const int pairi = blockIdx.y * 2 + pp;
        const int t0p   = pairi * 2;
        const int mytree = t0p + wx;

        float bias_v[4];
#pragma unroll
        for (int ni = 0; ni < 4; ++ni) {
            int nd = 16 * ni + l15;
            bias_v[ni] = (nd < NN) ? sb[mytree * NN + nd] : 0.f;
        }

        floatx4 acc[4][4];
#pragma unroll
        for (int i = 0; i < 4; ++i)
#pragma unroll
            for (int j = 0; j < 4; ++j) acc[i][j] = (floatx4)0.f;

        const _Float16* wg = swh + ((size_t)t0p * 64 + 32 * wid + Lr) * DD + csw * 8;

        // ---------------- GEMM1 K-loop (8 iters, BK=64) ----------------
        for (int k0 = 0; k0 < DD; k0 += BK) {
            __syncthreads();   // prior frag reads / epilogue aliasing done
#pragma unroll
            for (int j = 0; j < 4; ++j) {
                gl_lds16(xg + (size_t)(8 * j) * DD + k0,
                         smem + XS_OFF + (32 * wid + 8 * j) * 128);
                gl_lds16(wg + (size_t)(8 * j) * DD + k0,
                         smem + WL_OFF + (32 * wid + 8 * j) * 128);
            }
            __syncthreads();   // drains vmcnt(0): staged data visible
#pragma unroll
            for (int ks = 0; ks < 2; ++ks) {
                f16x8 af[4], bf[4];
#pragma unroll
                for (int mi = 0; mi < 4; ++mi) {
                    int r = 64 * wy + 16 * mi + l15;
                    af[mi] = *(const f16x8*)&xsh[r * 64 + (((ks << 2) | quad) ^ (r & 7)) * 8];
                }
#pragma unroll
                for (int ni = 0; ni < 4; ++ni) {
                    int r = 64 * wx + 16 * ni + l15;
                    bf[ni] = *(const f16x8*)&wlh[r * 64 + (((ks << 2) | quad) ^ (r & 7)) * 8];
                }
#pragma unroll
                for (int mi = 0; mi < 4; ++mi)
#pragma unroll
                    for (int ni = 0; ni < 4; ++ni)
                        acc[mi][ni] = __builtin_amdgcn_mfma_f32_16x16x32_f16(
                            af[mi], bf[ni], acc[mi][ni], 0, 0, 0);
            }
        }

        // ---------------- epilogue: two trees sequentially ----------------
        for (int tt = 0; tt < 2; ++tt) {
            __syncthreads();   // frag/GEMM2 reads done -> dec/lp/w2b reusable

            // stage this tree's w2T slice via global_load_lds (14 x 1KB)
            {
                const _Float16* w2g = w2T + (size_t)(t0p + tt) * CPAD * LL
                                      + (size_t)Lr * LL + csw * 8;
#pragma unroll
                for (int j = 0; j < 4; ++j) {
                    int J = wid * 4 + j;
                    if (J < 14)
                        gl_lds16(w2g + (size_t)J * 512, smem + W2B_OFF + J * 1024);
                }
            }
            // decisions for this tree -> dec[node][row] (b64 packed writes)
            if (wx == tt) {
#pragma unroll
                for (int mi = 0; mi < 4; ++mi) {
                    int r0 = 64 * wy + 16 * mi + 4 * quad;
#pragma unroll
                    for (int ni = 0; ni < 4; ++ni) {
                        int col = 16 * ni + l15;
                        float bsv = bias_v[ni];
                        f16x4 dv;
#pragma unroll
                        for (int r = 0; r < 4; ++r)
                            dv[r] = (_Float16)(1.f / (1.f + __expf(-(acc[mi][ni][r] + bsv))));
                        *(f16x4*)&dec[col * 132 + r0] = dv;
                    }
                }
            }
            __syncthreads();   // dec + w2b visible

            // leaf probs -> lp (swizzled A-frag layout)
            {
                float d0 = (float)dec[lrow];                       // node 0
                float p1 = half ? d0 : 1.f - d0;
                float d1 = (float)dec[(1 + half) * 132 + lrow];
#pragma unroll
                for (int b8 = 0; b8 < 4; ++b8) {
                    int i4 = b8 >> 1, i3 = b8 & 1;
                    float p2 = p1 * (i4 ? d1 : 1.f - d1);
                    float d2 = (float)dec[(3 + 2 * half + i4) * 132 + lrow];
                    float p3 = p2 * (i3 ? d2 : 1.f - d2);
                    float d3 = (float)dec[(7 + 4 * half + b8) * 132 + lrow];
                    f16x8 blk;
#pragma unroll
                    for (int i2 = 0; i2 < 2; ++i2) {
                        float p4 = p3 * (i2 ? d3 : 1.f - d3);
                        float d4 = (float)dec[(15 + 8 * half + 2 * b8 + i2) * 132 + lrow];
#pragma unroll
                        for (int i1 = 0; i1 < 2; ++i1) {
                            float p5 = p4 * (i1 ? d4 : 1.f - d4);
                            float d5 = (float)dec[(31 + 16 * half + 4 * b8 + 2 * i2 + i1) * 132 + lrow];
                            blk[i2 * 4 + i1 * 2 + 0] = (_Float16)(p5 * (1.f - d5));
                            blk[i2 * 4 + i1 * 2 + 1] = (_Float16)(p5 * d5);
                        }
                    }
                    int slot = (half * 4 + b8) ^ (lrow & 7);
                    *(f16x8*)&lph[lrow * 64 + slot * 8] = blk;
                }
            }
            __syncthreads();   // lp visible

            // GEMM2: rows 32*wid..+31, 112 cols, K=64; A from lp, B from w2b
#pragma unroll
            for (int ks = 0; ks < 2; ++ks) {
                f16x8 a2[2];
#pragma unroll
                for (int mi = 0; mi < 2; ++mi) {
                    int r = 32 * wid + 16 * mi + l15;
                    a2[mi] = *(const f16x8*)&lph[r * 64 + (((ks << 2) | quad) ^ (r & 7)) * 8];
                }
#pragma unroll
                for (int ni = 0; ni < 7; ++ni) {
                    int br = 16 * ni + l15;
                    f16x8 b2 = *(const f16x8*)&w2bh[br * 64 + (((ks << 2) | quad) ^ (br & 7)) * 8];
#pragma unroll
                    for (int mi = 0; mi < 2; ++mi)
                        oacc[mi][ni] = __builtin_amdgcn_mfma_f32_16x16x32_f16(
                            a2[mi], b2, oacc[mi][ni], 0, 0, 0);
                }
            }
        }
    }

    // --- atomic epilogue: once per block (4 trees pre-summed in regs) ---
#pragma unroll
    for (int ni = 0; ni < 7; ++ni) {
        int c = 16 * ni + l15;
        if (c < CC) {
#pragma unroll
            for (int mi = 0; mi < 2; ++mi) {
                int r0 = 32 * wid + 16 * mi + 4 * quad;
#pragma unroll
                for (int r = 0; r < 4; ++r)
                    atomicAdd(&out[(size_t)(b0 + r0 + r) * CC + c], oacc[mi][ni][r]);
            }
        }
    }
}

// ---------------------------------------------------------------------------
extern "C" void kernel_launch(void* const* d_in, const int* in_sizes, int n_in,
                              void* d_out, int out_size, void* d_ws, size_t ws_size,
                              hipStream_t stream) {
    const float* x  = (const float*)d_in[0];   // [8192][512]
    const float* sw = (const float*)d_in[1];   // [64][63][512]
    const float* sb = (const float*)d_in[2];   // [64][63]
    const float* ll = (const float*)d_in[3];   // [64][64][100]
    const float* tw = (const float*)d_in[4];   // [64]
    float* out = (float*)d_out;                // [8192][100]
    _Float16* xh  = (_Float16*)((char*)d_ws + XH_WS);
    _Float16* swh = (_Float16*)((char*)d_ws + SWH_WS);
    _Float16* w2T = (_Float16*)((char*)d_ws + W2T_WS);

    hipMemsetAsync(d_out, 0, (size_t)out_size * sizeof(float), stream);
    cvt_kernel<<<dim3(3072), 256, 0, stream>>>(x, sw, xh, swh);
    prep_w2_kernel<<<dim3(TREES * LL / 4), 256, 0, stream>>>(ll, tw, w2T);
    forest_kernel<<<dim3(BB / BM, 16), 256, 0, stream>>>(xh, swh, sb, w2T, out);
}

// Round 5
// 261.431 us; speedup vs baseline: 1.0702x; 1.0702x over previous
//
#include <hip/hip_runtime.h>

#define TREES 64
#define NN 63        // internal nodes per tree
#define LL 64        // leaves per tree
#define CC 100       // classes
#define CPAD 112     // classes padded to 7*16
#define DD 512       // feature dim
#define BB 8192      // batch
#define HALF 4096    // rows per half-batch

typedef __attribute__((ext_vector_type(8))) _Float16 f16x8;
typedef __attribute__((ext_vector_type(4))) _Float16 f16x4;
typedef __attribute__((ext_vector_type(4))) float floatx4;

// ---- workspace layout (bytes); ASSUMES ws_size >= ~45 MB ----
#define XH_WS   0            // x  tiled: [64 rb][8 kt][128 row][8 c][8] f16 = 8 MB
#define SWH_WS  8388608      // sw tiled: [32 cb][8 kt][128 col][8 c][8] f16 = 4 MB
#define W2T_WS  12582912     // [64 t][112 c][64 l] f16 = 0.92 MB
#define LP_WS   13500416     // [64 t][4096 row][64 l] f16 = 33.5 MB (per half)
// total 47054848 bytes

__device__ __forceinline__ void gl_lds16(const _Float16* g, char* lds) {
    __builtin_amdgcn_global_load_lds(
        (const __attribute__((address_space(1))) unsigned int*)g,
        (__attribute__((address_space(3))) unsigned int*)lds, 16, 0, 0);
}

__device__ __forceinline__ f16x8 cvt8(const float* s) {
    float4 a = *(const float4*)s, b = *(const float4*)(s + 4);
    f16x8 h;
    h[0]=(_Float16)a.x; h[1]=(_Float16)a.y; h[2]=(_Float16)a.z; h[3]=(_Float16)a.w;
    h[4]=(_Float16)b.x; h[5]=(_Float16)b.y; h[6]=(_Float16)b.z; h[7]=(_Float16)b.w;
    return h;
}

// ---------------------------------------------------------------------------
// Prep A: tile + swizzle-convert x and sw to f16.
// tile[row][c] holds global k-chunk (c ^ (row&7)) so a LINEAR global_load_lds
// copy leaves LDS pre-swizzled for conflict-free b128 frag reads.
// ---------------------------------------------------------------------------
__global__ __launch_bounds__(256) void cvt_kernel(
    const float* __restrict__ x, const float* __restrict__ sw,
    _Float16* __restrict__ xh, _Float16* __restrict__ swh)
{
    int i = blockIdx.x * 256 + threadIdx.x;
    if (i < 524288) {                        // x: 64rb*8kt*1024 chunks
        int tile = i >> 10, cidx = i & 1023;
        int row = cidx >> 3, c = cidx & 7;
        int rb = tile >> 3, kt = tile & 7;
        int gk = kt * 64 + ((c ^ (row & 7)) << 3);
        *(f16x8*)(xh + (size_t)i * 8) = cvt8(x + (size_t)(rb * 128 + row) * DD + gk);
    } else {
        int j = i - 524288;                  // sw: 32cb*8kt*1024 chunks
        if (j < 262144) {
            int tile = j >> 10, cidx = j & 1023;
            int col = cidx >> 3, c = cidx & 7;
            int cb = tile >> 3, kt = tile & 7;
            int tt = col >> 6, node = col & 63;
            f16x8 h = (f16x8)(_Float16)0.f;
            if (node < NN) {
                int gk = kt * 64 + ((c ^ (col & 7)) << 3);
                h = cvt8(sw + (size_t)((cb * 2 + tt) * NN + node) * DD + gk);
            }
            *(f16x8*)(swh + (size_t)j * 8) = h;
        }
    }
}

// ---------------------------------------------------------------------------
// Prep B: w2T[t][c][l] = f16( tree_w[t] * softmax(leaf_logits[t,l,:])[c] )
// ---------------------------------------------------------------------------
__global__ __launch_bounds__(256) void prep_w2_kernel(
    const float* __restrict__ leaf_logits,
    const float* __restrict__ tree_w,
    _Float16* __restrict__ w2T)
{
    int row  = blockIdx.x * 4 + (threadIdx.x >> 6);   // t*64 + l
    int lane = threadIdx.x & 63;
    int t = row >> 6, l = row & 63;
    const float* src = leaf_logits + (size_t)row * CC;
    float v0 = (lane < CC)      ? src[lane]      : -1e30f;
    float v1 = (lane + 64 < CC) ? src[lane + 64] : -1e30f;
    float m = fmaxf(v0, v1);
#pragma unroll
    for (int off = 32; off > 0; off >>= 1)
        m = fmaxf(m, __shfl_down(m, off, 64));
    m = __shfl(m, 0, 64);
    float e0 = (lane < CC)      ? __expf(v0 - m) : 0.f;
    float e1 = (lane + 64 < CC) ? __expf(v1 - m) : 0.f;
    float s = e0 + e1;
#pragma unroll
    for (int off = 32; off > 0; off >>= 1)
        s += __shfl_down(s, off, 64);
    s = __shfl(s, 0, 64);
    float scale = tree_w[t] / s;
    _Float16* base = w2T + (size_t)t * CPAD * LL;
    if (lane < CC)      base[(size_t)lane * LL + l]        = (_Float16)(e0 * scale);
    if (lane + 64 < CC) base[(size_t)(lane + 64) * LL + l] = (_Float16)(e1 * scale);
    if (lane < CPAD - CC) base[(size_t)(CC + lane) * LL + l] = (_Float16)0.f;
}

// ---------------------------------------------------------------------------
// Phase A: m97-style GEMM1 (128 rows x 128 cols[=2 trees], BK=64, 8 iters)
// + epilogue: biased logits -> LDS -> inline-sigmoid leafprob -> lp to ws.
// grid = (32 rowblocks, 32 colblocks); 256 threads (4 waves 2x2).
// ---------------------------------------------------------------------------
#define A_SMEM 33280
__global__ __launch_bounds__(256, 4) void gemm1_kernel(
    const _Float16* __restrict__ xh,
    const _Float16* __restrict__ swh,
    const float* __restrict__ sb,
    _Float16* __restrict__ lp_ws,
    int rb0)
{
    __shared__ __align__(16) char smem[A_SMEM];
    _Float16* xs  = (_Float16*)smem;             // [128][64] staging
    _Float16* wl  = (_Float16*)(smem + 16384);   // [128][64] staging
    _Float16* dec = (_Float16*)smem;             // [128 col][130] logits (alias)
    _Float16* lpl = (_Float16*)smem;             // [2][128][8 slot][8] (alias)

    const int tid  = threadIdx.x;
    const int lane = tid & 63;
    const int wid  = tid >> 6;
    const int wy   = wid >> 1;
    const int wx   = wid & 1;
    const int quad = lane >> 4;
    const int l15  = lane & 15;
    const int rb   = rb0 + blockIdx.x;           // absolute rowblock
    const int cb   = blockIdx.y;

    float bias_v[4];
    {
        int mytree = cb * 2 + wx;
#pragma unroll
        for (int ni = 0; ni < 4; ++ni) {
            int nd = 16 * ni + l15;
            bias_v[ni] = (nd < NN) ? sb[mytree * NN + nd] : 0.f;
        }
    }

    floatx4 acc[4][4];
#pragma unroll
    for (int i = 0; i < 4; ++i)
#pragma unroll
        for (int j = 0; j < 4; ++j) acc[i][j] = (floatx4)0.f;

    const _Float16* xtile = xh + (size_t)rb * 8 * 8192;
    const _Float16* wtile = swh + (size_t)cb * 8 * 8192;

    for (int kt = 0; kt < 8; ++kt) {
        __syncthreads();   // previous tile's frag reads done
#pragma unroll
        for (int j = 0; j < 4; ++j) {   // fully coalesced 1KB per instr
            gl_lds16(xtile + kt * 8192 + j * 2048 + wid * 512 + lane * 8,
                     smem + j * 4096 + wid * 1024);
            gl_lds16(wtile + kt * 8192 + j * 2048 + wid * 512 + lane * 8,
                     smem + 16384 + j * 4096 + wid * 1024);
        }
        __syncthreads();   // vmcnt(0) drain: tile visible
#pragma unroll
        for (int ks = 0; ks < 2; ++ks) {
            f16x8 af[4], bf[4];
#pragma unroll
            for (int mi = 0; mi < 4; ++mi) {
                int r = 64 * wy + 16 * mi + l15;
                af[mi] = *(const f16x8*)&xs[r * 64 + ((((ks << 2) | quad) ^ (r & 7)) << 3)];
            }
#pragma unroll
            for (int ni = 0; ni < 4; ++ni) {
                int r = 64 * wx + 16 * ni + l15;
                bf[ni] = *(const f16x8*)&wl[r * 64 + ((((ks << 2) | quad) ^ (r & 7)) << 3)];
            }
#pragma unroll
            for (int mi = 0; mi < 4; ++mi)
#pragma unroll
                for (int ni = 0; ni < 4; ++ni)
                    acc[mi][ni] = __builtin_amdgcn_mfma_f32_16x16x32_f16(
                        af[mi], bf[ni], acc[mi][ni], 0, 0, 0);
        }
    }
    __syncthreads();   // staging dead -> dec aliases it

    // biased logits -> dec[col][row], f16x4 packed stores
#pragma unroll
    for (int mi = 0; mi < 4; ++mi) {
        int r0 = 64 * wy + 16 * mi + 4 * quad;
#pragma unroll
        for (int ni = 0; ni < 4; ++ni) {
            int col = 64 * wx + 16 * ni + l15;
            f16x4 v;
#pragma unroll
            for (int r = 0; r < 4; ++r)
                v[r] = (_Float16)(acc[mi][ni][r] + bias_v[ni]);
            *(f16x4*)&dec[col * 130 + r0] = v;
        }
    }
    __syncthreads();

    // leafprob: thread = (tree tt, row lrow); sigmoid inline; results in regs
    const int tt   = tid >> 7;
    const int lrow = tid & 127;
    const int tb   = tt * 64;
    f16x8 lpreg[8];
    {
#define SIG(n) (1.f / (1.f + __expf(-(float)dec[(tb + (n)) * 130 + lrow])))
        float d0 = SIG(0);
#pragma unroll
        for (int h = 0; h < 2; ++h) {
            float p1 = h ? d0 : 1.f - d0;
            float d1 = SIG(1 + h);
#pragma unroll
            for (int b8 = 0; b8 < 4; ++b8) {
                int i4 = b8 >> 1, i3 = b8 & 1;
                float p2 = p1 * (i4 ? d1 : 1.f - d1);
                float d2 = SIG(3 + 2 * h + i4);
                float p3 = p2 * (i3 ? d2 : 1.f - d2);
                float d3 = SIG(7 + 4 * h + b8);
                f16x8 blk;
#pragma unroll
                for (int i2 = 0; i2 < 2; ++i2) {
                    float p4 = p3 * (i2 ? d3 : 1.f - d3);
                    float d4 = SIG(15 + 8 * h + 2 * b8 + i2);
#pragma unroll
                    for (int i1 = 0; i1 < 2; ++i1) {
                        float p5 = p4 * (i1 ? d4 : 1.f - d4);
                        float d5 = SIG(31 + 16 * h + 4 * b8 + 2 * i2 + i1);
                        blk[i2 * 4 + i1 * 2 + 0] = (_Float16)(p5 * (1.f - d5));
                        blk[i2 * 4 + i1 * 2 + 1] = (_Float16)(p5 * d5);
                    }
                }
                lpreg[h * 4 + b8] = blk;
            }
        }
#undef SIG
    }
    __syncthreads();   // all dec reads done -> lpl aliases it

    // regs -> LDS (slot-swizzled, conflict-free)
#pragma unroll
    for (int q = 0; q < 8; ++q)
        *(f16x8*)&lpl[tt * 8192 + lrow * 64 + ((q ^ (lrow & 7)) << 3)] = lpreg[q];
    __syncthreads();

    // cooperative coalesced store: lp_ws[t][rowloc][leaf]
    const int rloc0 = blockIdx.x * 128;
#pragma unroll
    for (int k = 0; k < 8; ++k) {
        int idx = k * 256 + tid;          // 0..2047
        int t2 = idx >> 10, rem = idx & 1023;
        int row = rem >> 3, cq = rem & 7;
        f16x8 v = *(const f16x8*)&lpl[t2 * 8192 + row * 64 + ((cq ^ (row & 7)) << 3)];
        *(f16x8*)(lp_ws + ((size_t)(cb * 2 + t2) * HALF + rloc0 + row) * 64 + cq * 8) = v;
    }
}

// ---------------------------------------------------------------------------
// Phase B: barrier-free batched GEMM2. block = 128 threads (2 waves),
// 64 rows x 112 cols x 4 trees; A/B frags direct from global (L3-hot).
// grid = (64 rowblocks, 16 treegroups).
// ---------------------------------------------------------------------------
__global__ __launch_bounds__(128, 4) void gemm2_kernel(
    const _Float16* __restrict__ lp_ws,   // [64][4096][64]
    const _Float16* __restrict__ w2T,     // [64][112][64]
    float* __restrict__ out,              // [8192][100]
    int rowbase)
{
    const int tid  = threadIdx.x;
    const int lane = tid & 63;
    const int wid  = tid >> 6;
    const int quad = lane >> 4;
    const int l15  = lane & 15;
    const int rloc = blockIdx.x * 64 + 32 * wid;
    const int tg   = blockIdx.y * 4;

    floatx4 oacc[2][7];
#pragma unroll
    for (int mi = 0; mi < 2; ++mi)
#pragma unroll
        for (int ni = 0; ni < 7; ++ni) oacc[mi][ni] = (floatx4)0.f;

#pragma unroll
    for (int k = 0; k < 4; ++k) {
        int t = tg + k;
        const _Float16* lpt = lp_ws + ((size_t)t * HALF + rloc) * 64;
        const _Float16* w2p = w2T + (size_t)t * CPAD * LL;
#pragma unroll
        for (int ks = 0; ks < 2; ++ks) {
            f16x8 a2[2];
#pragma unroll
            for (int mi = 0; mi < 2; ++mi)
                a2[mi] = *(const f16x8*)(lpt + (size_t)(16 * mi + l15) * 64 + ks * 32 + quad * 8);
#pragma unroll
            for (int ni = 0; ni < 7; ++ni) {
                f16x8 b2 = *(const f16x8*)(w2p + (size_t)(16 * ni + l15) * 64 + ks * 32 + quad * 8);
#pragma unroll
                for (int mi = 0; mi < 2; ++mi)
                    oacc[mi][ni] = __builtin_amdgcn_mfma_f32_16x16x32_f16(
                        a2[mi], b2, oacc[mi][ni], 0, 0, 0);
            }
        }
    }

#pragma unroll
    for (int ni = 0; ni < 7; ++ni) {
        int c = 16 * ni + l15;
        if (c < CC) {
#pragma unroll
            for (int mi = 0; mi < 2; ++mi) {
                int r0 = rowbase + rloc + 16 * mi + 4 * quad;
#pragma unroll
                for (int r = 0; r < 4; ++r)
                    atomicAdd(&out[(size_t)(r0 + r) * CC + c], oacc[mi][ni][r]);
            }
        }
    }
}

// ---------------------------------------------------------------------------
extern "C" void kernel_launch(void* const* d_in, const int* in_sizes, int n_in,
                              void* d_out, int out_size, void* d_ws, size_t ws_size,
                              hipStream_t stream) {
    const float* x  = (const float*)d_in[0];   // [8192][512]
    const float* sw = (const float*)d_in[1];   // [64][63][512]
    const float* sb = (const float*)d_in[2];   // [64][63]
    const float* ll = (const float*)d_in[3];   // [64][64][100]
    const float* tw = (const float*)d_in[4];   // [64]
    float* out = (float*)d_out;                // [8192][100]
    _Float16* xh  = (_Float16*)((char*)d_ws + XH_WS);
    _Float16* swh = (_Float16*)((char*)d_ws + SWH_WS);
    _Float16* w2T = (_Float16*)((char*)d_ws + W2T_WS);
    _Float16* lp  = (_Float16*)((char*)d_ws + LP_WS);

    hipMemsetAsync(d_out, 0, (size_t)out_size * sizeof(float), stream);
    cvt_kernel<<<dim3(3072), 256, 0, stream>>>(x, sw, xh, swh);
    prep_w2_kernel<<<dim3(TREES * LL / 4), 256, 0, stream>>>(ll, tw, w2T);
    for (int h = 0; h < 2; ++h) {
        gemm1_kernel<<<dim3(32, 32), 256, 0, stream>>>(xh, swh, sb, lp, h * 32);
        gemm2_kernel<<<dim3(64, 16), 128, 0, stream>>>(lp, w2T, out, h * HALF);
    }
}

// Round 6
// 231.897 us; speedup vs baseline: 1.2065x; 1.1274x over previous
//
#include <hip/hip_runtime.h>

#define TREES 64
#define NN 63        // internal nodes per tree
#define LL 64        // leaves per tree
#define CC 100       // classes
#define CPAD 112     // classes padded to 7*16
#define DD 512       // feature dim
#define BB 8192      // batch
#define HALF 4096    // rows per half-batch

typedef __attribute__((ext_vector_type(8))) _Float16 f16x8;
typedef __attribute__((ext_vector_type(4))) _Float16 f16x4;
typedef __attribute__((ext_vector_type(4))) float floatx4;

// ---- workspace layout (bytes); ws_size >= 47 MB proven in R5 ----
#define XH_WS   0            // x  tiled: [64 rb][8 kt][128 row][8 c][8] f16 = 8 MB
#define SWH_WS  8388608      // sw tiled: [32 cb][8 kt][128 col][8 c][8] f16 = 4 MB
#define W2T_WS  12582912     // [64 t][112 c][64 l] f16 = 0.92 MB
#define LP_WS   13500416     // [64 t][4096 row][64 l] f16 = 33.5 MB (per half)
// total 47054848 bytes

__device__ __forceinline__ void gl_lds16(const _Float16* g, char* lds) {
    __builtin_amdgcn_global_load_lds(
        (const __attribute__((address_space(1))) unsigned int*)g,
        (__attribute__((address_space(3))) unsigned int*)lds, 16, 0, 0);
}

__device__ __forceinline__ f16x8 cvt8(const float* s) {
    float4 a = *(const float4*)s, b = *(const float4*)(s + 4);
    f16x8 h;
    h[0]=(_Float16)a.x; h[1]=(_Float16)a.y; h[2]=(_Float16)a.z; h[3]=(_Float16)a.w;
    h[4]=(_Float16)b.x; h[5]=(_Float16)b.y; h[6]=(_Float16)b.z; h[7]=(_Float16)b.w;
    return h;
}

// ---------------------------------------------------------------------------
// Prep A: tile + swizzle-convert x and sw to f16.
// tile[row][c] holds global k-chunk (c ^ (row&7)) so a LINEAR global_load_lds
// copy leaves LDS pre-swizzled for conflict-free b128 frag reads.
// ---------------------------------------------------------------------------
__global__ __launch_bounds__(256) void cvt_kernel(
    const float* __restrict__ x, const float* __restrict__ sw,
    _Float16* __restrict__ xh, _Float16* __restrict__ swh)
{
    int i = blockIdx.x * 256 + threadIdx.x;
    if (i < 524288) {                        // x: 64rb*8kt*1024 chunks
        int tile = i >> 10, cidx = i & 1023;
        int row = cidx >> 3, c = cidx & 7;
        int rb = tile >> 3, kt = tile & 7;
        int gk = kt * 64 + ((c ^ (row & 7)) << 3);
        *(f16x8*)(xh + (size_t)i * 8) = cvt8(x + (size_t)(rb * 128 + row) * DD + gk);
    } else {
        int j = i - 524288;                  // sw: 32cb*8kt*1024 chunks
        if (j < 262144) {
            int tile = j >> 10, cidx = j & 1023;
            int col = cidx >> 3, c = cidx & 7;
            int cb = tile >> 3, kt = tile & 7;
            int tt = col >> 6, node = col & 63;
            f16x8 h = (f16x8)(_Float16)0.f;
            if (node < NN) {
                int gk = kt * 64 + ((c ^ (col & 7)) << 3);
                h = cvt8(sw + (size_t)((cb * 2 + tt) * NN + node) * DD + gk);
            }
            *(f16x8*)(swh + (size_t)j * 8) = h;
        }
    }
}

// ---------------------------------------------------------------------------
// Prep B: w2T[t][c][l] = f16( tree_w[t] * softmax(leaf_logits[t,l,:])[c] )
// ---------------------------------------------------------------------------
__global__ __launch_bounds__(256) void prep_w2_kernel(
    const float* __restrict__ leaf_logits,
    const float* __restrict__ tree_w,
    _Float16* __restrict__ w2T)
{
    int row  = blockIdx.x * 4 + (threadIdx.x >> 6);   // t*64 + l
    int lane = threadIdx.x & 63;
    int t = row >> 6, l = row & 63;
    const float* src = leaf_logits + (size_t)row * CC;
    float v0 = (lane < CC)      ? src[lane]      : -1e30f;
    float v1 = (lane + 64 < CC) ? src[lane + 64] : -1e30f;
    float m = fmaxf(v0, v1);
#pragma unroll
    for (int off = 32; off > 0; off >>= 1)
        m = fmaxf(m, __shfl_down(m, off, 64));
    m = __shfl(m, 0, 64);
    float e0 = (lane < CC)      ? __expf(v0 - m) : 0.f;
    float e1 = (lane + 64 < CC) ? __expf(v1 - m) : 0.f;
    float s = e0 + e1;
#pragma unroll
    for (int off = 32; off > 0; off >>= 1)
        s += __shfl_down(s, off, 64);
    s = __shfl(s, 0, 64);
    float scale = tree_w[t] / s;
    _Float16* base = w2T + (size_t)t * CPAD * LL;
    if (lane < CC)      base[(size_t)lane * LL + l]        = (_Float16)(e0 * scale);
    if (lane + 64 < CC) base[(size_t)(lane + 64) * LL + l] = (_Float16)(e1 * scale);
    if (lane < CPAD - CC) base[(size_t)(CC + lane) * LL + l] = (_Float16)0.f;
}

// ---------------------------------------------------------------------------
// Phase A: m97-style GEMM1 (128 rows x 128 cols[=2 trees], BK=64, 8 iters)
// + epilogue: biased logits -> LDS -> inline-sigmoid leafprob -> lp to ws.
// grid = (32 rowblocks, 32 colblocks); 256 threads (4 waves 2x2).
// ---------------------------------------------------------------------------
#define A_SMEM 33280
__global__ __launch_bounds__(256, 4) void gemm1_kernel(
    const _Float16* __restrict__ xh,
    const _Float16* __restrict__ swh,
    const float* __restrict__ sb,
    _Float16* __restrict__ lp_ws,
    int rb0)
{
    __shared__ __align__(16) char smem[A_SMEM];
    _Float16* xs  = (_Float16*)smem;             // [128][64] staging
    _Float16* wl  = (_Float16*)(smem + 16384);   // [128][64] staging
    _Float16* dec = (_Float16*)smem;             // [128 col][130] logits (alias)
    _Float16* lpl = (_Float16*)smem;             // [2][128][8 slot][8] (alias)

    const int tid  = threadIdx.x;
    const int lane = tid & 63;
    const int wid  = tid >> 6;
    const int wy   = wid >> 1;
    const int wx   = wid & 1;
    const int quad = lane >> 4;
    const int l15  = lane & 15;
    const int rb   = rb0 + blockIdx.x;           // absolute rowblock
    const int cb   = blockIdx.y;

    float bias_v[4];
    {
        int mytree = cb * 2 + wx;
#pragma unroll
        for (int ni = 0; ni < 4; ++ni) {
            int nd = 16 * ni + l15;
            bias_v[ni] = (nd < NN) ? sb[mytree * NN + nd] : 0.f;
        }
    }

    floatx4 acc[4][4];
#pragma unroll
    for (int i = 0; i < 4; ++i)
#pragma unroll
        for (int j = 0; j < 4; ++j) acc[i][j] = (floatx4)0.f;

    const _Float16* xtile = xh + (size_t)rb * 8 * 8192;
    const _Float16* wtile = swh + (size_t)cb * 8 * 8192;

    for (int kt = 0; kt < 8; ++kt) {
        __syncthreads();   // previous tile's frag reads done
#pragma unroll
        for (int j = 0; j < 4; ++j) {   // fully coalesced 1KB per instr
            gl_lds16(xtile + kt * 8192 + j * 2048 + wid * 512 + lane * 8,
                     smem + j * 4096 + wid * 1024);
            gl_lds16(wtile + kt * 8192 + j * 2048 + wid * 512 + lane * 8,
                     smem + 16384 + j * 4096 + wid * 1024);
        }
        __syncthreads();   // vmcnt(0) drain: tile visible
#pragma unroll
        for (int ks = 0; ks < 2; ++ks) {
            f16x8 af[4], bf[4];
#pragma unroll
            for (int mi = 0; mi < 4; ++mi) {
                int r = 64 * wy + 16 * mi + l15;
                af[mi] = *(const f16x8*)&xs[r * 64 + ((((ks << 2) | quad) ^ (r & 7)) << 3)];
            }
#pragma unroll
            for (int ni = 0; ni < 4; ++ni) {
                int r = 64 * wx + 16 * ni + l15;
                bf[ni] = *(const f16x8*)&wl[r * 64 + ((((ks << 2) | quad) ^ (r & 7)) << 3)];
            }
#pragma unroll
            for (int mi = 0; mi < 4; ++mi)
#pragma unroll
                for (int ni = 0; ni < 4; ++ni)
                    acc[mi][ni] = __builtin_amdgcn_mfma_f32_16x16x32_f16(
                        af[mi], bf[ni], acc[mi][ni], 0, 0, 0);
        }
    }
    __syncthreads();   // staging dead -> dec aliases it

    // biased logits -> dec[col][row], f16x4 packed stores
#pragma unroll
    for (int mi = 0; mi < 4; ++mi) {
        int r0 = 64 * wy + 16 * mi + 4 * quad;
#pragma unroll
        for (int ni = 0; ni < 4; ++ni) {
            int col = 64 * wx + 16 * ni + l15;
            f16x4 v;
#pragma unroll
            for (int r = 0; r < 4; ++r)
                v[r] = (_Float16)(acc[mi][ni][r] + bias_v[ni]);
            *(f16x4*)&dec[col * 130 + r0] = v;
        }
    }
    __syncthreads();

    // leafprob: thread = (tree tt, row lrow); sigmoid inline; results in regs
    const int tt   = tid >> 7;
    const int lrow = tid & 127;
    const int tb   = tt * 64;
    f16x8 lpreg[8];
    {
#define SIG(n) (1.f / (1.f + __expf(-(float)dec[(tb + (n)) * 130 + lrow])))
        float d0 = SIG(0);
#pragma unroll
        for (int h = 0; h < 2; ++h) {
            float p1 = h ? d0 : 1.f - d0;
            float d1 = SIG(1 + h);
#pragma unroll
            for (int b8 = 0; b8 < 4; ++b8) {
                int i4 = b8 >> 1, i3 = b8 & 1;
                float p2 = p1 * (i4 ? d1 : 1.f - d1);
                float d2 = SIG(3 + 2 * h + i4);
                float p3 = p2 * (i3 ? d2 : 1.f - d2);
                float d3 = SIG(7 + 4 * h + b8);
                f16x8 blk;
#pragma unroll
                for (int i2 = 0; i2 < 2; ++i2) {
                    float p4 = p3 * (i2 ? d3 : 1.f - d3);
                    float d4 = SIG(15 + 8 * h + 2 * b8 + i2);
#pragma unroll
                    for (int i1 = 0; i1 < 2; ++i1) {
                        float p5 = p4 * (i1 ? d4 : 1.f - d4);
                        float d5 = SIG(31 + 16 * h + 4 * b8 + 2 * i2 + i1);
                        blk[i2 * 4 + i1 * 2 + 0] = (_Float16)(p5 * (1.f - d5));
                        blk[i2 * 4 + i1 * 2 + 1] = (_Float16)(p5 * d5);
                    }
                }
                lpreg[h * 4 + b8] = blk;
            }
        }
#undef SIG
    }
    __syncthreads();   // all dec reads done -> lpl aliases it

    // regs -> LDS (slot-swizzled, conflict-free)
#pragma unroll
    for (int q = 0; q < 8; ++q)
        *(f16x8*)&lpl[tt * 8192 + lrow * 64 + ((q ^ (lrow & 7)) << 3)] = lpreg[q];
    __syncthreads();

    // cooperative coalesced store: lp_ws[t][rowloc][leaf]
    const int rloc0 = blockIdx.x * 128;
#pragma unroll
    for (int k = 0; k < 8; ++k) {
        int idx = k * 256 + tid;          // 0..2047
        int t2 = idx >> 10, rem = idx & 1023;
        int row = rem >> 3, cq = rem & 7;
        f16x8 v = *(const f16x8*)&lpl[t2 * 8192 + row * 64 + ((cq ^ (row & 7)) << 3)];
        *(f16x8*)(lp_ws + ((size_t)(cb * 2 + t2) * HALF + rloc0 + row) * 64 + cq * 8) = v;
    }
}

// ---------------------------------------------------------------------------
// Phase B: batched GEMM2, atomic-minimized. Each block owns 32 rows x 112
// cols exclusively within its treegroup (16 trees) -> one atomic per out
// element per treegroup (4x fewer ops, 4-way line contention vs 16).
// grid = (128 rowblocks, 4 treegroups); 128 threads (2 waves x 16 rows).
// ---------------------------------------------------------------------------
__global__ __launch_bounds__(128, 4) void gemm2_kernel(
    const _Float16* __restrict__ lp_ws,   // [64][4096][64]
    const _Float16* __restrict__ w2T,     // [64][112][64]
    float* __restrict__ out,              // [8192][100]
    int rowbase)
{
    const int tid  = threadIdx.x;
    const int lane = tid & 63;
    const int wid  = tid >> 6;
    const int quad = lane >> 4;
    const int l15  = lane & 15;
    const int rloc = blockIdx.x * 32 + 16 * wid;
    const int tg   = blockIdx.y * 16;

    floatx4 oacc[7];
#pragma unroll
    for (int ni = 0; ni < 7; ++ni) oacc[ni] = (floatx4)0.f;

#pragma unroll 4
    for (int k = 0; k < 16; ++k) {
        int t = tg + k;
        const _Float16* lpt = lp_ws + ((size_t)t * HALF + rloc) * 64;
        const _Float16* w2p = w2T + (size_t)t * CPAD * LL;
#pragma unroll
        for (int ks = 0; ks < 2; ++ks) {
            f16x8 a2 = *(const f16x8*)(lpt + (size_t)l15 * 64 + ks * 32 + quad * 8);
#pragma unroll
            for (int ni = 0; ni < 7; ++ni) {
                f16x8 b2 = *(const f16x8*)(w2p + (size_t)(16 * ni + l15) * 64 + ks * 32 + quad * 8);
                oacc[ni] = __builtin_amdgcn_mfma_f32_16x16x32_f16(a2, b2, oacc[ni], 0, 0, 0);
            }
        }
    }

#pragma unroll
    for (int ni = 0; ni < 7; ++ni) {
        int c = 16 * ni + l15;
        if (c < CC) {
            int r0 = rowbase + rloc + 4 * quad;
#pragma unroll
            for (int r = 0; r < 4; ++r)
                atomicAdd(&out[(size_t)(r0 + r) * CC + c], oacc[ni][r]);
        }
    }
}

// ---------------------------------------------------------------------------
extern "C" void kernel_launch(void* const* d_in, const int* in_sizes, int n_in,
                              void* d_out, int out_size, void* d_ws, size_t ws_size,
                              hipStream_t stream) {
    const float* x  = (const float*)d_in[0];   // [8192][512]
    const float* sw = (const float*)d_in[1];   // [64][63][512]
    const float* sb = (const float*)d_in[2];   // [64][63]
    const float* ll = (const float*)d_in[3];   // [64][64][100]
    const float* tw = (const float*)d_in[4];   // [64]
    float* out = (float*)d_out;                // [8192][100]
    _Float16* xh  = (_Float16*)((char*)d_ws + XH_WS);
    _Float16* swh = (_Float16*)((char*)d_ws + SWH_WS);
    _Float16* w2T = (_Float16*)((char*)d_ws + W2T_WS);
    _Float16* lp  = (_Float16*)((char*)d_ws + LP_WS);

    hipMemsetAsync(d_out, 0, (size_t)out_size * sizeof(float), stream);
    cvt_kernel<<<dim3(3072), 256, 0, stream>>>(x, sw, xh, swh);
    prep_w2_kernel<<<dim3(TREES * LL / 4), 256, 0, stream>>>(ll, tw, w2T);
    for (int h = 0; h < 2; ++h) {
        gemm1_kernel<<<dim3(32, 32), 256, 0, stream>>>(xh, swh, sb, lp, h * 32);
        gemm2_kernel<<<dim3(128, 4), 128, 0, stream>>>(lp, w2T, out, h * HALF);
    }
}

// Round 7
// 172.934 us; speedup vs baseline: 1.6178x; 1.3410x over previous
//
#include <hip/hip_runtime.h>

#define TREES 64
#define NN 63        // internal nodes per tree
#define LL 64        // leaves per tree
#define CC 100       // classes
#define CPAD 112     // classes padded to 7*16
#define DD 512       // feature dim
#define BB 8192      // batch

typedef __attribute__((ext_vector_type(8))) _Float16 f16x8;
typedef __attribute__((ext_vector_type(4))) _Float16 f16x4;
typedef __attribute__((ext_vector_type(4))) float floatx4;

// ---- workspace layout (bytes); ws_size ~= 256 MiB (poison fill = 268 MB) ----
#define XH_WS   0            // x  tiled: [64 rb][8 kt][128 row][8 c][8] f16 = 8 MB
#define SWH_WS  8388608      // sw tiled: [32 cb][8 kt][128 col][8 c][8] f16 = 4 MB
#define W2T_WS  12582912     // [64 t][112 c][64 l] f16 (chunk-swizzled) = 0.92 MB
#define LP_WS   13500416     // [64 t][8192 row][64 l] f16 (chunk-swizzled) = 67 MB
#define PART_WS 80609280     // [8 tg][8192 row][112 c] f32 = 29.4 MB
// total ~110 MB

__device__ __forceinline__ void gl_lds16(const _Float16* g, char* lds) {
    __builtin_amdgcn_global_load_lds(
        (const __attribute__((address_space(1))) unsigned int*)g,
        (__attribute__((address_space(3))) unsigned int*)lds, 16, 0, 0);
}

__device__ __forceinline__ f16x8 cvt8(const float* s) {
    float4 a = *(const float4*)s, b = *(const float4*)(s + 4);
    f16x8 h;
    h[0]=(_Float16)a.x; h[1]=(_Float16)a.y; h[2]=(_Float16)a.z; h[3]=(_Float16)a.w;
    h[4]=(_Float16)b.x; h[5]=(_Float16)b.y; h[6]=(_Float16)b.z; h[7]=(_Float16)b.w;
    return h;
}

// ---------------------------------------------------------------------------
// Prep A: tile + swizzle-convert x and sw to f16 (same as R5/R6).
// ---------------------------------------------------------------------------
__global__ __launch_bounds__(256) void cvt_kernel(
    const float* __restrict__ x, const float* __restrict__ sw,
    _Float16* __restrict__ xh, _Float16* __restrict__ swh)
{
    int i = blockIdx.x * 256 + threadIdx.x;
    if (i < 524288) {                        // x: 64rb*8kt*1024 chunks
        int tile = i >> 10, cidx = i & 1023;
        int row = cidx >> 3, c = cidx & 7;
        int rb = tile >> 3, kt = tile & 7;
        int gk = kt * 64 + ((c ^ (row & 7)) << 3);
        *(f16x8*)(xh + (size_t)i * 8) = cvt8(x + (size_t)(rb * 128 + row) * DD + gk);
    } else {
        int j = i - 524288;                  // sw: 32cb*8kt*1024 chunks
        if (j < 262144) {
            int tile = j >> 10, cidx = j & 1023;
            int col = cidx >> 3, c = cidx & 7;
            int cb = tile >> 3, kt = tile & 7;
            int tt = col >> 6, node = col & 63;
            f16x8 h = (f16x8)(_Float16)0.f;
            if (node < NN) {
                int gk = kt * 64 + ((c ^ (col & 7)) << 3);
                h = cvt8(sw + (size_t)((cb * 2 + tt) * NN + node) * DD + gk);
            }
            *(f16x8*)(swh + (size_t)j * 8) = h;
        }
    }
}

// ---------------------------------------------------------------------------
// Prep B: w2T[t][c][l'] = f16( tree_w[t]*softmax(leaf_logits[t,l,:])[c] ),
// leaf chunk PRE-SWIZZLED: l' = ((l>>3) ^ (c&7))*8 + (l&7) so a linear
// global_load_lds copy leaves LDS conflict-free for B-frag reads.
// ---------------------------------------------------------------------------
__global__ __launch_bounds__(256) void prep_w2_kernel(
    const float* __restrict__ leaf_logits,
    const float* __restrict__ tree_w,
    _Float16* __restrict__ w2T)
{
    int row  = blockIdx.x * 4 + (threadIdx.x >> 6);   // t*64 + l
    int lane = threadIdx.x & 63;
    int t = row >> 6, l = row & 63;
    const float* src = leaf_logits + (size_t)row * CC;
    float v0 = (lane < CC)      ? src[lane]      : -1e30f;
    float v1 = (lane + 64 < CC) ? src[lane + 64] : -1e30f;
    float m = fmaxf(v0, v1);
#pragma unroll
    for (int off = 32; off > 0; off >>= 1)
        m = fmaxf(m, __shfl_down(m, off, 64));
    m = __shfl(m, 0, 64);
    float e0 = (lane < CC)      ? __expf(v0 - m) : 0.f;
    float e1 = (lane + 64 < CC) ? __expf(v1 - m) : 0.f;
    float s = e0 + e1;
#pragma unroll
    for (int off = 32; off > 0; off >>= 1)
        s += __shfl_down(s, off, 64);
    s = __shfl(s, 0, 64);
    float scale = tree_w[t] / s;
    _Float16* base = w2T + (size_t)t * CPAD * LL;
#define LSWZ(c) ((((l >> 3) ^ ((c) & 7)) << 3) | (l & 7))
    if (lane < CC)      base[(size_t)lane * LL + LSWZ(lane)]               = (_Float16)(e0 * scale);
    if (lane + 64 < CC) base[(size_t)(lane + 64) * LL + LSWZ(lane + 64)]   = (_Float16)(e1 * scale);
    if (lane < CPAD - CC) base[(size_t)(CC + lane) * LL + LSWZ(CC + lane)] = (_Float16)0.f;
#undef LSWZ
}

// ---------------------------------------------------------------------------
// Phase A: GEMM1 (128 rows x 128 cols[=2 trees], BK=64, 8 iters) + epilogue
// leafprob -> lp to ws (chunk-swizzled layout, so gemm2 can linear-copy).
// grid = (64 rowblocks, 32 colblocks); 256 threads (4 waves 2x2).
// ---------------------------------------------------------------------------
#define A_SMEM 33280
__global__ __launch_bounds__(256, 4) void gemm1_kernel(
    const _Float16* __restrict__ xh,
    const _Float16* __restrict__ swh,
    const float* __restrict__ sb,
    _Float16* __restrict__ lp_ws)
{
    __shared__ __align__(16) char smem[A_SMEM];
    _Float16* xs  = (_Float16*)smem;             // [128][64] staging
    _Float16* wl  = (_Float16*)(smem + 16384);   // [128][64] staging
    _Float16* dec = (_Float16*)smem;             // [128 col][130] logits (alias)
    _Float16* lpl = (_Float16*)smem;             // [2][128][8 slot][8] (alias)

    const int tid  = threadIdx.x;
    const int lane = tid & 63;
    const int wid  = tid >> 6;
    const int wy   = wid >> 1;
    const int wx   = wid & 1;
    const int quad = lane >> 4;
    const int l15  = lane & 15;
    const int rb   = blockIdx.x;
    const int cb   = blockIdx.y;

    float bias_v[4];
    {
        int mytree = cb * 2 + wx;
#pragma unroll
        for (int ni = 0; ni < 4; ++ni) {
            int nd = 16 * ni + l15;
            bias_v[ni] = (nd < NN) ? sb[mytree * NN + nd] : 0.f;
        }
    }

    floatx4 acc[4][4];
#pragma unroll
    for (int i = 0; i < 4; ++i)
#pragma unroll
        for (int j = 0; j < 4; ++j) acc[i][j] = (floatx4)0.f;

    const _Float16* xtile = xh + (size_t)rb * 8 * 8192;
    const _Float16* wtile = swh + (size_t)cb * 8 * 8192;

    for (int kt = 0; kt < 8; ++kt) {
        __syncthreads();   // previous tile's frag reads done
#pragma unroll
        for (int j = 0; j < 4; ++j) {   // fully coalesced 1KB per instr
            gl_lds16(xtile + kt * 8192 + j * 2048 + wid * 512 + lane * 8,
                     smem + j * 4096 + wid * 1024);
            gl_lds16(wtile + kt * 8192 + j * 2048 + wid * 512 + lane * 8,
                     smem + 16384 + j * 4096 + wid * 1024);
        }
        __syncthreads();   // vmcnt(0) drain: tile visible
#pragma unroll
        for (int ks = 0; ks < 2; ++ks) {
            f16x8 af[4], bf[4];
#pragma unroll
            for (int mi = 0; mi < 4; ++mi) {
                int r = 64 * wy + 16 * mi + l15;
                af[mi] = *(const f16x8*)&xs[r * 64 + ((((ks << 2) | quad) ^ (r & 7)) << 3)];
            }
#pragma unroll
            for (int ni = 0; ni < 4; ++ni) {
                int r = 64 * wx + 16 * ni + l15;
                bf[ni] = *(const f16x8*)&wl[r * 64 + ((((ks << 2) | quad) ^ (r & 7)) << 3)];
            }
#pragma unroll
            for (int mi = 0; mi < 4; ++mi)
#pragma unroll
                for (int ni = 0; ni < 4; ++ni)
                    acc[mi][ni] = __builtin_amdgcn_mfma_f32_16x16x32_f16(
                        af[mi], bf[ni], acc[mi][ni], 0, 0, 0);
        }
    }
    __syncthreads();   // staging dead -> dec aliases it

    // biased logits -> dec[col][row], f16x4 packed stores
#pragma unroll
    for (int mi = 0; mi < 4; ++mi) {
        int r0 = 64 * wy + 16 * mi + 4 * quad;
#pragma unroll
        for (int ni = 0; ni < 4; ++ni) {
            int col = 64 * wx + 16 * ni + l15;
            f16x4 v;
#pragma unroll
            for (int r = 0; r < 4; ++r)
                v[r] = (_Float16)(acc[mi][ni][r] + bias_v[ni]);
            *(f16x4*)&dec[col * 130 + r0] = v;
        }
    }
    __syncthreads();

    // leafprob: thread = (tree tt, row lrow); sigmoid inline
    const int tt   = tid >> 7;
    const int lrow = tid & 127;
    const int tb   = tt * 64;
    f16x8 lpreg[8];
    {
#define SIG(n) (1.f / (1.f + __expf(-(float)dec[(tb + (n)) * 130 + lrow])))
        float d0 = SIG(0);
#pragma unroll
        for (int h = 0; h < 2; ++h) {
            float p1 = h ? d0 : 1.f - d0;
            float d1 = SIG(1 + h);
#pragma unroll
            for (int b8 = 0; b8 < 4; ++b8) {
                int i4 = b8 >> 1, i3 = b8 & 1;
                float p2 = p1 * (i4 ? d1 : 1.f - d1);
                float d2 = SIG(3 + 2 * h + i4);
                float p3 = p2 * (i3 ? d2 : 1.f - d2);
                float d3 = SIG(7 + 4 * h + b8);
                f16x8 blk;
#pragma unroll
                for (int i2 = 0; i2 < 2; ++i2) {
                    float p4 = p3 * (i2 ? d3 : 1.f - d3);
                    float d4 = SIG(15 + 8 * h + 2 * b8 + i2);
#pragma unroll
                    for (int i1 = 0; i1 < 2; ++i1) {
                        float p5 = p4 * (i1 ? d4 : 1.f - d4);
                        float d5 = SIG(31 + 16 * h + 4 * b8 + 2 * i2 + i1);
                        blk[i2 * 4 + i1 * 2 + 0] = (_Float16)(p5 * (1.f - d5));
                        blk[i2 * 4 + i1 * 2 + 1] = (_Float16)(p5 * d5);
                    }
                }
                lpreg[h * 4 + b8] = blk;
            }
        }
#undef SIG
    }
    __syncthreads();   // all dec reads done -> lpl aliases it

    // regs -> LDS (slot-swizzled)
#pragma unroll
    for (int q = 0; q < 8; ++q)
        *(f16x8*)&lpl[tt * 8192 + lrow * 64 + ((q ^ (lrow & 7)) << 3)] = lpreg[q];
    __syncthreads();

    // cooperative LINEAR store: lp_ws keeps the swizzled chunk order so
    // gemm2's global_load_lds linear copy is conflict-free at frag time.
    const int rloc0 = blockIdx.x * 128;
#pragma unroll
    for (int k = 0; k < 8; ++k) {
        int idx = k * 256 + tid;          // 0..2047
        int t2 = idx >> 10, rem = idx & 1023;
        int row = rem >> 3, cq = rem & 7;
        f16x8 v = *(const f16x8*)&lpl[t2 * 8192 + row * 64 + cq * 8];
        *(f16x8*)(lp_ws + ((size_t)(cb * 2 + t2) * BB + rloc0 + row) * 64 + cq * 8) = v;
    }
}

// ---------------------------------------------------------------------------
// Phase B: LDS-staged GEMM2. Block = 256 threads (4 waves), 256 rows x 112
// cols; K-loop over 8 trees: stage A (32KB) + B (14KB) via global_load_lds,
// wave = 64 rows x 112 cols. Writes fp32 partials (no atomics).
// grid = (32 rowblocks, 8 treegroups).
// ---------------------------------------------------------------------------
#define B_SMEM 47104   // A 32768 + B 14336
__global__ __launch_bounds__(256, 2) void gemm2_kernel(
    const _Float16* __restrict__ lp_ws,   // [64][8192][64] swizzled
    const _Float16* __restrict__ w2T,     // [64][112][64] swizzled
    float* __restrict__ part)             // [8][8192][112]
{
    __shared__ __align__(16) char smem[B_SMEM];
    _Float16* As = (_Float16*)smem;             // [256 row][64]
    _Float16* Bs = (_Float16*)(smem + 32768);   // [112 col][64]

    const int tid  = threadIdx.x;
    const int lane = tid & 63;
    const int wid  = tid >> 6;
    const int quad = lane >> 4;
    const int l15  = lane & 15;
    const int r0   = blockIdx.x * 256;
    const int tg   = blockIdx.y;

    floatx4 oacc[4][7];
#pragma unroll
    for (int mi = 0; mi < 4; ++mi)
#pragma unroll
        for (int ni = 0; ni < 7; ++ni) oacc[mi][ni] = (floatx4)0.f;

    for (int k = 0; k < 8; ++k) {
        int t = tg * 8 + k;
        const _Float16* pA = lp_ws + ((size_t)t * BB + r0) * 64;
        const _Float16* pB = w2T + (size_t)t * CPAD * LL;
        __syncthreads();   // previous tree's frag reads done
#pragma unroll
        for (int j = 0; j < 8; ++j) {      // A: 32 x 1KB wave-chunks
            int m = j * 4 + wid;
            gl_lds16(pA + m * 512 + lane * 8, smem + m * 1024);
        }
#pragma unroll
        for (int j = 0; j < 4; ++j) {      // B: 14 x 1KB wave-chunks
            int m = j * 4 + wid;
            if (m < 14)
                gl_lds16(pB + m * 512 + lane * 8, smem + 32768 + m * 1024);
        }
        __syncthreads();   // vmcnt(0) drain: tiles visible
#pragma unroll
        for (int ks = 0; ks < 2; ++ks) {
            f16x8 af[4], bf[7];
#pragma unroll
            for (int mi = 0; mi < 4; ++mi) {
                int r = 64 * wid + 16 * mi + l15;
                af[mi] = *(const f16x8*)&As[r * 64 + ((((ks << 2) | quad) ^ (r & 7)) << 3)];
            }
#pragma unroll
            for (int ni = 0; ni < 7; ++ni) {
                int c = 16 * ni + l15;
                bf[ni] = *(const f16x8*)&Bs[c * 64 + ((((ks << 2) | quad) ^ (c & 7)) << 3)];
            }
#pragma unroll
            for (int mi = 0; mi < 4; ++mi)
#pragma unroll
                for (int ni = 0; ni < 7; ++ni)
                    oacc[mi][ni] = __builtin_amdgcn_mfma_f32_16x16x32_f16(
                        af[mi], bf[ni], oacc[mi][ni], 0, 0, 0);
        }
    }

    // plain fp32 stores to this treegroup's private partial
    float* pp = part + (size_t)tg * BB * CPAD;
#pragma unroll
    for (int mi = 0; mi < 4; ++mi) {
        int rr = r0 + 64 * wid + 16 * mi + 4 * quad;
#pragma unroll
        for (int ni = 0; ni < 7; ++ni) {
            int c = 16 * ni + l15;
#pragma unroll
            for (int r = 0; r < 4; ++r)
                pp[(size_t)(rr + r) * CPAD + c] = oacc[mi][ni][r];
        }
    }
}

// ---------------------------------------------------------------------------
// Reduce: out[row][c] = sum_g part[g][row][c].  2 rows per 256-thread block.
// ---------------------------------------------------------------------------
__global__ __launch_bounds__(256) void reduce_kernel(
    const float* __restrict__ part, float* __restrict__ out)
{
    int row = blockIdx.x * 2 + (threadIdx.x >> 7);
    int c   = threadIdx.x & 127;
    if (c < CC) {
        float s = 0.f;
#pragma unroll
        for (int g = 0; g < 8; ++g)
            s += part[((size_t)g * BB + row) * CPAD + c];
        out[(size_t)row * CC + c] = s;
    }
}

// ---------------------------------------------------------------------------
extern "C" void kernel_launch(void* const* d_in, const int* in_sizes, int n_in,
                              void* d_out, int out_size, void* d_ws, size_t ws_size,
                              hipStream_t stream) {
    const float* x  = (const float*)d_in[0];   // [8192][512]
    const float* sw = (const float*)d_in[1];   // [64][63][512]
    const float* sb = (const float*)d_in[2];   // [64][63]
    const float* ll = (const float*)d_in[3];   // [64][64][100]
    const float* tw = (const float*)d_in[4];   // [64]
    float* out = (float*)d_out;                // [8192][100]
    _Float16* xh   = (_Float16*)((char*)d_ws + XH_WS);
    _Float16* swh  = (_Float16*)((char*)d_ws + SWH_WS);
    _Float16* w2T  = (_Float16*)((char*)d_ws + W2T_WS);
    _Float16* lp   = (_Float16*)((char*)d_ws + LP_WS);
    float*    part = (float*)((char*)d_ws + PART_WS);

    cvt_kernel<<<dim3(3072), 256, 0, stream>>>(x, sw, xh, swh);
    prep_w2_kernel<<<dim3(TREES * LL / 4), 256, 0, stream>>>(ll, tw, w2T);
    gemm1_kernel<<<dim3(64, 32), 256, 0, stream>>>(xh, swh, sb, lp);
    gemm2_kernel<<<dim3(32, 8), 256, 0, stream>>>(lp, w2T, part);
    reduce_kernel<<<dim3(BB / 2), 256, 0, stream>>>(part, out);
}

// Round 8
// 161.580 us; speedup vs baseline: 1.7315x; 1.0703x over previous
//
#include <hip/hip_runtime.h>

#define TREES 64
#define NN 63        // internal nodes per tree
#define LL 64        // leaves per tree
#define CC 100       // classes
#define CPAD 112     // classes padded to 7*16
#define DD 512       // feature dim
#define BB 8192      // batch

typedef __attribute__((ext_vector_type(8))) _Float16 f16x8;
typedef __attribute__((ext_vector_type(4))) _Float16 f16x4;
typedef __attribute__((ext_vector_type(4))) float floatx4;

// ---- workspace layout (bytes); ws_size ~= 256 MiB ----
#define XH_WS   0            // x  tiled: [64 rb][8 kt][128 row][8 c][8] f16 = 8 MB
#define SWH_WS  8388608      // sw tiled: [32 cb][8 kt][128 col][8 c][8] f16 = 4 MB
#define W2T_WS  12582912     // [64 t][112 c][64 l] f16 (chunk-swizzled) = 0.92 MB
#define LP_WS   13500416     // [64 t][8192 row][64 l] f16 (chunk-swizzled) = 67 MB

__device__ __forceinline__ void gl_lds16(const _Float16* g, char* lds) {
    __builtin_amdgcn_global_load_lds(
        (const __attribute__((address_space(1))) unsigned int*)g,
        (__attribute__((address_space(3))) unsigned int*)lds, 16, 0, 0);
}

__device__ __forceinline__ f16x8 cvt8(const float* s) {
    float4 a = *(const float4*)s, b = *(const float4*)(s + 4);
    f16x8 h;
    h[0]=(_Float16)a.x; h[1]=(_Float16)a.y; h[2]=(_Float16)a.z; h[3]=(_Float16)a.w;
    h[4]=(_Float16)b.x; h[5]=(_Float16)b.y; h[6]=(_Float16)b.z; h[7]=(_Float16)b.w;
    return h;
}

// ---------------------------------------------------------------------------
// Prep (merged): blocks 0..3071 tile+convert x/sw; blocks 3072..4095 build
// w2T[t][c][l'] with leaf chunk pre-swizzled (l' = ((l>>3)^(c&7))*8 + (l&7)).
// ---------------------------------------------------------------------------
__global__ __launch_bounds__(256) void prep_kernel(
    const float* __restrict__ x, const float* __restrict__ sw,
    const float* __restrict__ leaf_logits, const float* __restrict__ tree_w,
    _Float16* __restrict__ xh, _Float16* __restrict__ swh,
    _Float16* __restrict__ w2T)
{
    if (blockIdx.x < 3072) {
        int i = blockIdx.x * 256 + threadIdx.x;
        if (i < 524288) {                        // x: 64rb*8kt*1024 chunks
            int tile = i >> 10, cidx = i & 1023;
            int row = cidx >> 3, c = cidx & 7;
            int rb = tile >> 3, kt = tile & 7;
            int gk = kt * 64 + ((c ^ (row & 7)) << 3);
            *(f16x8*)(xh + (size_t)i * 8) = cvt8(x + (size_t)(rb * 128 + row) * DD + gk);
        } else {
            int j = i - 524288;                  // sw: 32cb*8kt*1024 chunks
            if (j < 262144) {
                int tile = j >> 10, cidx = j & 1023;
                int col = cidx >> 3, c = cidx & 7;
                int cb = tile >> 3, kt = tile & 7;
                int tt = col >> 6, node = col & 63;
                f16x8 h = (f16x8)(_Float16)0.f;
                if (node < NN) {
                    int gk = kt * 64 + ((c ^ (col & 7)) << 3);
                    h = cvt8(sw + (size_t)((cb * 2 + tt) * NN + node) * DD + gk);
                }
                *(f16x8*)(swh + (size_t)j * 8) = h;
            }
        }
    } else {
        int row  = (blockIdx.x - 3072) * 4 + (threadIdx.x >> 6);  // t*64 + l
        int lane = threadIdx.x & 63;
        int t = row >> 6, l = row & 63;
        const float* src = leaf_logits + (size_t)row * CC;
        float v0 = (lane < CC)      ? src[lane]      : -1e30f;
        float v1 = (lane + 64 < CC) ? src[lane + 64] : -1e30f;
        float m = fmaxf(v0, v1);
#pragma unroll
        for (int off = 32; off > 0; off >>= 1)
            m = fmaxf(m, __shfl_down(m, off, 64));
        m = __shfl(m, 0, 64);
        float e0 = (lane < CC)      ? __expf(v0 - m) : 0.f;
        float e1 = (lane + 64 < CC) ? __expf(v1 - m) : 0.f;
        float s = e0 + e1;
#pragma unroll
        for (int off = 32; off > 0; off >>= 1)
            s += __shfl_down(s, off, 64);
        s = __shfl(s, 0, 64);
        float scale = tree_w[t] / s;
        _Float16* base = w2T + (size_t)t * CPAD * LL;
#define LSWZ(c) ((((l >> 3) ^ ((c) & 7)) << 3) | (l & 7))
        if (lane < CC)      base[(size_t)lane * LL + LSWZ(lane)]               = (_Float16)(e0 * scale);
        if (lane + 64 < CC) base[(size_t)(lane + 64) * LL + LSWZ(lane + 64)]   = (_Float16)(e1 * scale);
        if (lane < CPAD - CC) base[(size_t)(CC + lane) * LL + LSWZ(CC + lane)] = (_Float16)0.f;
#undef LSWZ
    }
}

// ---------------------------------------------------------------------------
// Phase A: GEMM1 (128 rows x 128 cols[=2 trees], BK=64, 8 iters) + epilogue
// leafprob -> lp to ws (chunk-swizzled). Unchanged from R7.
// grid = (64 rowblocks, 32 colblocks); 256 threads (4 waves 2x2).
// ---------------------------------------------------------------------------
#define A_SMEM 33280
__global__ __launch_bounds__(256, 4) void gemm1_kernel(
    const _Float16* __restrict__ xh,
    const _Float16* __restrict__ swh,
    const float* __restrict__ sb,
    _Float16* __restrict__ lp_ws)
{
    __shared__ __align__(16) char smem[A_SMEM];
    _Float16* xs  = (_Float16*)smem;             // [128][64] staging
    _Float16* wl  = (_Float16*)(smem + 16384);   // [128][64] staging
    _Float16* dec = (_Float16*)smem;             // [128 col][130] logits (alias)
    _Float16* lpl = (_Float16*)smem;             // [2][128][8 slot][8] (alias)

    const int tid  = threadIdx.x;
    const int lane = tid & 63;
    const int wid  = tid >> 6;
    const int wy   = wid >> 1;
    const int wx   = wid & 1;
    const int quad = lane >> 4;
    const int l15  = lane & 15;
    const int rb   = blockIdx.x;
    const int cb   = blockIdx.y;

    float bias_v[4];
    {
        int mytree = cb * 2 + wx;
#pragma unroll
        for (int ni = 0; ni < 4; ++ni) {
            int nd = 16 * ni + l15;
            bias_v[ni] = (nd < NN) ? sb[mytree * NN + nd] : 0.f;
        }
    }

    floatx4 acc[4][4];
#pragma unroll
    for (int i = 0; i < 4; ++i)
#pragma unroll
        for (int j = 0; j < 4; ++j) acc[i][j] = (floatx4)0.f;

    const _Float16* xtile = xh + (size_t)rb * 8 * 8192;
    const _Float16* wtile = swh + (size_t)cb * 8 * 8192;

    for (int kt = 0; kt < 8; ++kt) {
        __syncthreads();   // previous tile's frag reads done
#pragma unroll
        for (int j = 0; j < 4; ++j) {   // fully coalesced 1KB per instr
            gl_lds16(xtile + kt * 8192 + j * 2048 + wid * 512 + lane * 8,
                     smem + j * 4096 + wid * 1024);
            gl_lds16(wtile + kt * 8192 + j * 2048 + wid * 512 + lane * 8,
                     smem + 16384 + j * 4096 + wid * 1024);
        }
        __syncthreads();   // vmcnt(0) drain: tile visible
#pragma unroll
        for (int ks = 0; ks < 2; ++ks) {
            f16x8 af[4], bf[4];
#pragma unroll
            for (int mi = 0; mi < 4; ++mi) {
                int r = 64 * wy + 16 * mi + l15;
                af[mi] = *(const f16x8*)&xs[r * 64 + ((((ks << 2) | quad) ^ (r & 7)) << 3)];
            }
#pragma unroll
            for (int ni = 0; ni < 4; ++ni) {
                int r = 64 * wx + 16 * ni + l15;
                bf[ni] = *(const f16x8*)&wl[r * 64 + ((((ks << 2) | quad) ^ (r & 7)) << 3)];
            }
#pragma unroll
            for (int mi = 0; mi < 4; ++mi)
#pragma unroll
                for (int ni = 0; ni < 4; ++ni)
                    acc[mi][ni] = __builtin_amdgcn_mfma_f32_16x16x32_f16(
                        af[mi], bf[ni], acc[mi][ni], 0, 0, 0);
        }
    }
    __syncthreads();   // staging dead -> dec aliases it

    // biased logits -> dec[col][row], f16x4 packed stores
#pragma unroll
    for (int mi = 0; mi < 4; ++mi) {
        int r0 = 64 * wy + 16 * mi + 4 * quad;
#pragma unroll
        for (int ni = 0; ni < 4; ++ni) {
            int col = 64 * wx + 16 * ni + l15;
            f16x4 v;
#pragma unroll
            for (int r = 0; r < 4; ++r)
                v[r] = (_Float16)(acc[mi][ni][r] + bias_v[ni]);
            *(f16x4*)&dec[col * 130 + r0] = v;
        }
    }
    __syncthreads();

    // leafprob: thread = (tree tt, row lrow); sigmoid inline
    const int tt   = tid >> 7;
    const int lrow = tid & 127;
    const int tb   = tt * 64;
    f16x8 lpreg[8];
    {
#define SIG(n) (1.f / (1.f + __expf(-(float)dec[(tb + (n)) * 130 + lrow])))
        float d0 = SIG(0);
#pragma unroll
        for (int h = 0; h < 2; ++h) {
            float p1 = h ? d0 : 1.f - d0;
            float d1 = SIG(1 + h);
#pragma unroll
            for (int b8 = 0; b8 < 4; ++b8) {
                int i4 = b8 >> 1, i3 = b8 & 1;
                float p2 = p1 * (i4 ? d1 : 1.f - d1);
                float d2 = SIG(3 + 2 * h + i4);
                float p3 = p2 * (i3 ? d2 : 1.f - d2);
                float d3 = SIG(7 + 4 * h + b8);
                f16x8 blk;
#pragma unroll
                for (int i2 = 0; i2 < 2; ++i2) {
                    float p4 = p3 * (i2 ? d3 : 1.f - d3);
                    float d4 = SIG(15 + 8 * h + 2 * b8 + i2);
#pragma unroll
                    for (int i1 = 0; i1 < 2; ++i1) {
                        float p5 = p4 * (i1 ? d4 : 1.f - d4);
                        float d5 = SIG(31 + 16 * h + 4 * b8 + 2 * i2 + i1);
                        blk[i2 * 4 + i1 * 2 + 0] = (_Float16)(p5 * (1.f - d5));
                        blk[i2 * 4 + i1 * 2 + 1] = (_Float16)(p5 * d5);
                    }
                }
                lpreg[h * 4 + b8] = blk;
            }
        }
#undef SIG
    }
    __syncthreads();   // all dec reads done -> lpl aliases it

#pragma unroll
    for (int q = 0; q < 8; ++q)
        *(f16x8*)&lpl[tt * 8192 + lrow * 64 + ((q ^ (lrow & 7)) << 3)] = lpreg[q];
    __syncthreads();

    // cooperative LINEAR store keeping swizzled chunk order
    const int rloc0 = blockIdx.x * 128;
#pragma unroll
    for (int k = 0; k < 8; ++k) {
        int idx = k * 256 + tid;          // 0..2047
        int t2 = idx >> 10, rem = idx & 1023;
        int row = rem >> 3, cq = rem & 7;
        f16x8 v = *(const f16x8*)&lpl[t2 * 8192 + row * 64 + cq * 8];
        *(f16x8*)(lp_ws + ((size_t)(cb * 2 + t2) * BB + rloc0 + row) * 64 + cq * 8) = v;
    }
}

// ---------------------------------------------------------------------------
// Phase B (fused gemm2+reduce): grid 256 blocks x 512 threads (8 waves).
// Block = 32 rows x 112 cols; trees split 8-ways across waves (8 each).
// A/B frags direct from global (swizzle folded into address), manual 2-stage
// register pipeline for load ILP. 2-phase LDS reduce -> direct store to out.
// ---------------------------------------------------------------------------
#define RSTR 113                 // padded row stride (floats) in reduce region
#define RREG (32 * RSTR)         // 3616 floats per region
__global__ __launch_bounds__(512, 2) void gemm2_kernel(
    const _Float16* __restrict__ lp_ws,   // [64][8192][64] swizzled chunks
    const _Float16* __restrict__ w2T,     // [64][112][64] swizzled chunks
    float* __restrict__ out)              // [8192][100]
{
    __shared__ float red[4 * RREG];       // 57856 B

    const int tid  = threadIdx.x;
    const int lane = tid & 63;
    const int wv   = tid >> 6;            // 0..7
    const int quad = lane >> 4;
    const int l15  = lane & 15;
    const int r0   = blockIdx.x * 32;
    const int t0   = wv * 8;              // this wave's first tree

    floatx4 oacc[2][7];
#pragma unroll
    for (int mi = 0; mi < 2; ++mi)
#pragma unroll
        for (int ni = 0; ni < 7; ++ni) oacc[mi][ni] = (floatx4)0.f;

    // swizzled chunk offset per ks (row&7 == c&7 == l15&7 here)
    const int sw0 = ((0 | quad) ^ (l15 & 7)) << 3;
    const int sw1 = ((4 | quad) ^ (l15 & 7)) << 3;
    const _Float16* aBase = lp_ws + ((size_t)t0 * BB + r0 + l15) * 64;
    const _Float16* bBase = w2T + (size_t)t0 * CPAD * LL + (size_t)l15 * 64;

    f16x8 ab[2][2], bb[2][7];
    // step s = t8*2 + ks  (16 steps); load step into buf, mfma previous
#define LOADS(s, buf)                                                          \
    {                                                                          \
        int t8 = (s) >> 1;                                                     \
        int sw = ((s) & 1) ? sw1 : sw0;                                        \
        const _Float16* ap = aBase + (size_t)t8 * (BB * 64);                   \
        const _Float16* bp = bBase + (size_t)t8 * (CPAD * LL);                 \
        ab[buf][0] = *(const f16x8*)(ap + sw);                                 \
        ab[buf][1] = *(const f16x8*)(ap + 16 * 64 + sw);                       \
        _Pragma("unroll")                                                      \
        for (int ni = 0; ni < 7; ++ni)                                         \
            bb[buf][ni] = *(const f16x8*)(bp + ni * 16 * 64 + sw);             \
    }
#define MFMAS(buf)                                                             \
    {                                                                          \
        _Pragma("unroll")                                                      \
        for (int mi = 0; mi < 2; ++mi)                                         \
            _Pragma("unroll")                                                  \
            for (int ni = 0; ni < 7; ++ni)                                     \
                oacc[mi][ni] = __builtin_amdgcn_mfma_f32_16x16x32_f16(         \
                    ab[buf][mi], bb[buf][ni], oacc[mi][ni], 0, 0, 0);          \
    }
    LOADS(0, 0)
#pragma unroll
    for (int s = 0; s < 15; ++s) {
        LOADS(s + 1, (s + 1) & 1)
        MFMAS(s & 1)
    }
    MFMAS(1)
#undef LOADS
#undef MFMAS

    // phase 1: waves 4..7 write partials to regions 0..3
    if (wv >= 4) {
        float* rg = &red[(wv - 4) * RREG];
#pragma unroll
        for (int mi = 0; mi < 2; ++mi)
#pragma unroll
            for (int ni = 0; ni < 7; ++ni)
#pragma unroll
                for (int r = 0; r < 4; ++r)
                    rg[(16 * mi + 4 * quad + r) * RSTR + 16 * ni + l15] = oacc[mi][ni][r];
    }
    __syncthreads();
    // phase 2: waves 0..3 add their acc into region wv
    if (wv < 4) {
        float* rg = &red[wv * RREG];
#pragma unroll
        for (int mi = 0; mi < 2; ++mi)
#pragma unroll
            for (int ni = 0; ni < 7; ++ni)
#pragma unroll
                for (int r = 0; r < 4; ++r)
                    rg[(16 * mi + 4 * quad + r) * RSTR + 16 * ni + l15] += oacc[mi][ni][r];
    }
    __syncthreads();
    // final: sum 4 regions, store. thread -> (row = tid>>4, cols k*16+(tid&15))
    {
        int row = tid >> 4, c16 = tid & 15;
#pragma unroll
        for (int k = 0; k < 7; ++k) {
            int col = k * 16 + c16;
            float s = 0.f;
#pragma unroll
            for (int g = 0; g < 4; ++g)
                s += red[g * RREG + row * RSTR + col];
            if (col < CC)
                out[(size_t)(r0 + row) * CC + col] = s;
        }
    }
}

// ---------------------------------------------------------------------------
extern "C" void kernel_launch(void* const* d_in, const int* in_sizes, int n_in,
                              void* d_out, int out_size, void* d_ws, size_t ws_size,
                              hipStream_t stream) {
    const float* x  = (const float*)d_in[0];   // [8192][512]
    const float* sw = (const float*)d_in[1];   // [64][63][512]
    const float* sb = (const float*)d_in[2];   // [64][63]
    const float* ll = (const float*)d_in[3];   // [64][64][100]
    const float* tw = (const float*)d_in[4];   // [64]
    float* out = (float*)d_out;                // [8192][100]
    _Float16* xh  = (_Float16*)((char*)d_ws + XH_WS);
    _Float16* swh = (_Float16*)((char*)d_ws + SWH_WS);
    _Float16* w2T = (_Float16*)((char*)d_ws + W2T_WS);
    _Float16* lp  = (_Float16*)((char*)d_ws + LP_WS);

    prep_kernel<<<dim3(4096), 256, 0, stream>>>(x, sw, ll, tw, xh, swh, w2T);
    gemm1_kernel<<<dim3(64, 32), 256, 0, stream>>>(xh, swh, sb, lp);
    gemm2_kernel<<<dim3(256), 512, 0, stream>>>(lp, w2T, out);
}